// Round 3
// baseline (22688.412 us; speedup 1.0000x reference)
//
#include <hip/hip_runtime.h>
#include <cmath>

// Problem constants (fixed by the reference).
#define SEQ   4096
#define INP   1024
#define HID   1024
#define G4    4096   // 4*HID

// ---------------------------------------------------------------------------
// Kernel 1: xg[t][r] = dot(emb[inputs[t]], W_ih[r]) + b_ih[r] + b_hh[r]
// 64x64 output tile per block, 256 threads, 4x4 micro-tile, fp32 VALU.
// ---------------------------------------------------------------------------
__global__ __launch_bounds__(256) void xg_gemm_kernel(
    const int* __restrict__ inputs,
    const float* __restrict__ emb,
    const float* __restrict__ W_ih,
    const float* __restrict__ b_ih,
    const float* __restrict__ b_hh,
    float* __restrict__ xg)
{
    __shared__ __align__(16) float As[16][68];
    __shared__ __align__(16) float Bs[16][68];
    __shared__ int toks[64];

    const int tid = threadIdx.x;
    const int bt = blockIdx.y * 64;
    const int br = blockIdx.x * 64;

    if (tid < 64) toks[tid] = inputs[bt + tid];
    __syncthreads();

    const int tx = tid & 15;
    const int ty = tid >> 4;
    const int si = tid >> 2;
    const int sk = (tid & 3) * 4;

    float acc[4][4] = {};

    for (int kk = 0; kk < INP; kk += 16) {
        float4 av = *(const float4*)(emb  + (size_t)toks[si] * INP + kk + sk);
        float4 bv = *(const float4*)(W_ih + (size_t)(br + si) * INP + kk + sk);
        As[sk+0][si] = av.x; As[sk+1][si] = av.y; As[sk+2][si] = av.z; As[sk+3][si] = av.w;
        Bs[sk+0][si] = bv.x; Bs[sk+1][si] = bv.y; Bs[sk+2][si] = bv.z; Bs[sk+3][si] = bv.w;
        __syncthreads();
        #pragma unroll
        for (int k = 0; k < 16; ++k) {
            float4 a = *(const float4*)&As[k][ty * 4];
            float4 b = *(const float4*)&Bs[k][tx * 4];
            float ar[4] = {a.x, a.y, a.z, a.w};
            float brr[4] = {b.x, b.y, b.z, b.w};
            #pragma unroll
            for (int iy = 0; iy < 4; ++iy)
                #pragma unroll
                for (int ix = 0; ix < 4; ++ix)
                    acc[iy][ix] += ar[iy] * brr[ix];
        }
        __syncthreads();
    }

    const int r0 = br + tx * 4;
    float4 bias;
    bias.x = b_ih[r0+0] + b_hh[r0+0];
    bias.y = b_ih[r0+1] + b_hh[r0+1];
    bias.z = b_ih[r0+2] + b_hh[r0+2];
    bias.w = b_ih[r0+3] + b_hh[r0+3];
    #pragma unroll
    for (int iy = 0; iy < 4; ++iy) {
        float4 o;
        o.x = acc[iy][0] + bias.x;
        o.y = acc[iy][1] + bias.y;
        o.z = acc[iy][2] + bias.z;
        o.w = acc[iy][3] + bias.w;
        *(float4*)(xg + (size_t)(bt + ty * 4 + iy) * G4 + r0) = o;
    }
}

// ---------------------------------------------------------------------------
__device__ __forceinline__ float fast_sigmoid(float x) {
    x = fminf(fmaxf(x, -30.f), 30.f);
    return __builtin_amdgcn_rcpf(1.0f + __expf(-x));
}
__device__ __forceinline__ float fast_tanh(float x) {
    x = fminf(fmaxf(x, -15.f), 15.f);
    float e = __expf(2.0f * x);
    return (e - 1.0f) * __builtin_amdgcn_rcpf(e + 1.0f);
}

__device__ __forceinline__ unsigned long long mb_load(const unsigned long long* p) {
    return __hip_atomic_load(p, __ATOMIC_RELAXED, __HIP_MEMORY_SCOPE_AGENT);
}

// ---------------------------------------------------------------------------
// Kernel 2: persistent cooperative LSTM scan with per-XCD mailbox replicas.
//
// 64 WGs x 1024 threads. Wave wv (0..15) of WG w owns h element j = w*16+wv.
// Lane layout within a wave: q = lane>>4 = gate (i,f,g,o); kc = lane&15 =
// 64-float chunk of h. Thread holds W_hh[q*1024+j][kc*64 .. +64) in regs.
//
// Mailboxes: mbox[replica(8)][parity(2)][1024] of u64 (tag<<32|f32bits).
//  - Producers: after computing h, lanes 0..7 of the wave scatter the tagged
//    value to all 8 replicas (one store instruction).
//  - Consumers: poll ONLY replica[my_xcd] (runtime HW_REG_XCC_ID), so each
//    64B line is polled by ~8 WGs instead of 64 -> no same-line MALL queueing.
//  - Polling is 4-deep pipelined (4 outstanding loads round-robin) so the
//    poll issue period is ~L/4 instead of L.
// Slot-reuse safety (parity + tag): producer writes tag t+1 only after
// observing ALL tag-t values, which happens-after every WG's stores of tag t,
// which happen-after that WG's reads of parity (t+1)&1 for step t-1. So no
// slot is overwritten before all its readers are done. Poison 0xAA... never
// matches a real tag (tags <= 4096).
// ---------------------------------------------------------------------------
__global__ __launch_bounds__(1024) void lstm_kernel(
    const float* __restrict__ xg,
    const float* __restrict__ W_hh,
    const float* __restrict__ h0,
    const float* __restrict__ c0,
    unsigned long long* __restrict__ mbox,   // 8 * 2 * 1024 entries
    float* __restrict__ out)
{
    const int w    = blockIdx.x;   // 0..63
    const int tid  = threadIdx.x;  // 0..1023
    const int lane = tid & 63;
    const int wv   = tid >> 6;     // wave 0..15 -> h element j = w*16+wv
    const int q    = lane >> 4;    // gate 0..3
    const int kc   = lane & 15;    // h chunk index
    const int j    = w * 16 + wv;
    const int row  = q * HID + j;

    // Which XCD is this WG on? (performance-only; correctness is scope-based)
    unsigned int xcc;
    asm volatile("s_getreg_b32 %0, hwreg(HW_REG_XCC_ID)" : "=s"(xcc));
    xcc &= 7;

    // Persistent W_hh fragment.
    float wreg[64];
    {
        const float* wp = W_hh + (size_t)row * HID + kc * 64;
        #pragma unroll
        for (int m = 0; m < 16; ++m) {
            float4 v = *(const float4*)(wp + 4 * m);
            wreg[4*m+0] = v.x; wreg[4*m+1] = v.y; wreg[4*m+2] = v.z; wreg[4*m+3] = v.w;
        }
    }

    float c = c0[j];

    // Seed h0 with tag 0 into parity-0 slots of ALL replicas.
    {
        unsigned long long pk = (unsigned long long)__float_as_uint(h0[j]);
        if (lane < 8) {
            __hip_atomic_store(mbox + ((size_t)lane * 2 + 0) * 1024 + j, pk,
                               __ATOMIC_RELAXED, __HIP_MEMORY_SCOPE_AGENT);
        }
    }

    __shared__ __align__(16) float hs[2][16 * 68];
    __shared__ float xgs[2][64];

    const int lofs = (tid >> 6) * 68 + (tid & 63);
    const bool hasx = (tid < 64);
    const size_t xgofs = (size_t)(tid >> 4) * HID + w * 16 + (tid & 15);

    for (int t = 0; t < SEQ; ++t) {
        const int par = t & 1;
        const unsigned long long* slot =
            mbox + ((size_t)xcc * 2 + par) * 1024 + tid;

        // xg load issued before the poll; its latency hides under the wait.
        float xv = 0.f;
        if (hasx) xv = xg[(size_t)t * G4 + xgofs];

        // 4-deep pipelined poll of this thread's single entry.
        const unsigned int tg = (unsigned int)t;
        unsigned long long v;
        {
            unsigned long long p0 = mb_load(slot);
            unsigned long long p1 = mb_load(slot);
            unsigned long long p2 = mb_load(slot);
            unsigned long long p3 = mb_load(slot);
            for (;;) {
                if ((unsigned int)(p0 >> 32) == tg) { v = p0; break; }
                p0 = mb_load(slot);
                if ((unsigned int)(p1 >> 32) == tg) { v = p1; break; }
                p1 = mb_load(slot);
                if ((unsigned int)(p2 >> 32) == tg) { v = p2; break; }
                p2 = mb_load(slot);
                if ((unsigned int)(p3 >> 32) == tg) { v = p3; break; }
                p3 = mb_load(slot);
            }
        }

        hs[par][lofs] = __uint_as_float((unsigned int)v);
        if (hasx) xgs[par][tid] = xv;
        __syncthreads();

        // dot(wreg, h chunk kc): 16 x ds_read_b128 (2-way bank alias = free).
        const float* hp = hs[par] + kc * 68;
        float sx = 0.f, sy = 0.f, sz = 0.f, sw = 0.f;
        #pragma unroll
        for (int m = 0; m < 16; ++m) {
            float4 hv = *(const float4*)(hp + 4 * m);
            sx += wreg[4*m+0] * hv.x;
            sy += wreg[4*m+1] * hv.y;
            sz += wreg[4*m+2] * hv.z;
            sw += wreg[4*m+3] * hv.w;
        }
        float s = (sx + sy) + (sz + sw);
        s += __shfl_xor(s, 1);
        s += __shfl_xor(s, 2);
        s += __shfl_xor(s, 4);
        s += __shfl_xor(s, 8);
        float gi = __shfl(s, 0)  + xgs[par][ 0 + wv];
        float gf = __shfl(s, 16) + xgs[par][16 + wv];
        float gg = __shfl(s, 32) + xgs[par][32 + wv];
        float go = __shfl(s, 48) + xgs[par][48 + wv];

        float ig = fast_sigmoid(gi);
        float fg = fast_sigmoid(gf);
        float gc = fast_tanh(gg);
        float og = fast_sigmoid(go);
        c = fg * c + ig * gc;
        float h = og * fast_tanh(c);

        // Scatter tagged h to all 8 replicas (lanes 0..7, one instruction).
        {
            unsigned long long pk =
                ((unsigned long long)(unsigned int)(t + 1) << 32) |
                (unsigned long long)__float_as_uint(h);
            if (lane < 8) {
                __hip_atomic_store(
                    mbox + ((size_t)lane * 2 + ((t + 1) & 1)) * 1024 + j, pk,
                    __ATOMIC_RELAXED, __HIP_MEMORY_SCOPE_AGENT);
            }
        }
        // No trailing barrier: hs/xgs are parity double-buffered; the next
        // write to this parity is ordered after next step's barrier.
    }

    // ------------------- final log_softmax (WG 0 only) -------------------
    if (w != 0) return;

    float a;
    {
        const unsigned int tg = (unsigned int)SEQ;  // SEQ even -> parity 0
        const unsigned long long* slot = mbox + ((size_t)xcc * 2 + 0) * 1024 + tid;
        unsigned long long v;
        do {
            v = mb_load(slot);
        } while ((unsigned int)(v >> 32) != tg);
        a = __uint_as_float((unsigned int)v);
    }

    __shared__ float rmax[16];
    __shared__ float rsum[16];

    float lm = a;
    #pragma unroll
    for (int d = 1; d < 64; d <<= 1) lm = fmaxf(lm, __shfl_xor(lm, d));
    if (lane == 0) rmax[wv] = lm;
    __syncthreads();
    float gm = rmax[0];
    #pragma unroll
    for (int i = 1; i < 16; ++i) gm = fmaxf(gm, rmax[i]);

    float ls = expf(a - gm);
    #pragma unroll
    for (int d = 1; d < 64; d <<= 1) ls += __shfl_xor(ls, d);
    if (lane == 0) rsum[wv] = ls;
    __syncthreads();
    float tot = rsum[0];
    #pragma unroll
    for (int i = 1; i < 16; ++i) tot += rsum[i];
    const float lse = gm + logf(tot);

    out[tid] = a - lse;
}

// ---------------------------------------------------------------------------
extern "C" void kernel_launch(void* const* d_in, const int* in_sizes, int n_in,
                              void* d_out, int out_size, void* d_ws, size_t ws_size,
                              hipStream_t stream)
{
    const int*   inputs = (const int*)d_in[0];
    const float* emb    = (const float*)d_in[1];
    const float* W_ih   = (const float*)d_in[2];
    const float* W_hh   = (const float*)d_in[3];
    const float* b_ih   = (const float*)d_in[4];
    const float* b_hh   = (const float*)d_in[5];
    const float* h0     = (const float*)d_in[6];
    const float* c0     = (const float*)d_in[7];
    float* out = (float*)d_out;

    // Workspace: [0, 64MB) xg ; [64MB, +128KB) mbox (8 replicas x 2 x 1024 u64).
    float* xg = (float*)d_ws;
    unsigned long long* mbox =
        (unsigned long long*)((char*)d_ws + (size_t)SEQ * G4 * sizeof(float));

    dim3 g1(G4 / 64, SEQ / 64), b1(256);
    hipLaunchKernelGGL(xg_gemm_kernel, g1, b1, 0, stream,
                       inputs, emb, W_ih, b_ih, b_hh, xg);

    void* args[] = { (void*)&xg, (void*)&W_hh, (void*)&h0, (void*)&c0,
                     (void*)&mbox, (void*)&out };
    hipLaunchCooperativeKernel((void*)lstm_kernel, dim3(64), dim3(1024),
                               args, 0u, stream);
}

// Round 4
// 9869.071 us; speedup vs baseline: 2.2989x; 2.2989x over previous
//
#include <hip/hip_runtime.h>
#include <cmath>

// Problem constants (fixed by the reference).
#define SEQ   4096
#define INP   1024
#define HID   1024
#define G4    4096   // 4*HID

// ---------------------------------------------------------------------------
// Kernel 1: xg[t][r] = dot(emb[inputs[t]], W_ih[r]) + b_ih[r] + b_hh[r]
// 64x64 output tile per block, 256 threads, 4x4 micro-tile, fp32 VALU.
// ---------------------------------------------------------------------------
__global__ __launch_bounds__(256) void xg_gemm_kernel(
    const int* __restrict__ inputs,
    const float* __restrict__ emb,
    const float* __restrict__ W_ih,
    const float* __restrict__ b_ih,
    const float* __restrict__ b_hh,
    float* __restrict__ xg)
{
    __shared__ __align__(16) float As[16][68];
    __shared__ __align__(16) float Bs[16][68];
    __shared__ int toks[64];

    const int tid = threadIdx.x;
    const int bt = blockIdx.y * 64;
    const int br = blockIdx.x * 64;

    if (tid < 64) toks[tid] = inputs[bt + tid];
    __syncthreads();

    const int tx = tid & 15;
    const int ty = tid >> 4;
    const int si = tid >> 2;
    const int sk = (tid & 3) * 4;

    float acc[4][4] = {};

    for (int kk = 0; kk < INP; kk += 16) {
        float4 av = *(const float4*)(emb  + (size_t)toks[si] * INP + kk + sk);
        float4 bv = *(const float4*)(W_ih + (size_t)(br + si) * INP + kk + sk);
        As[sk+0][si] = av.x; As[sk+1][si] = av.y; As[sk+2][si] = av.z; As[sk+3][si] = av.w;
        Bs[sk+0][si] = bv.x; Bs[sk+1][si] = bv.y; Bs[sk+2][si] = bv.z; Bs[sk+3][si] = bv.w;
        __syncthreads();
        #pragma unroll
        for (int k = 0; k < 16; ++k) {
            float4 a = *(const float4*)&As[k][ty * 4];
            float4 b = *(const float4*)&Bs[k][tx * 4];
            float ar[4] = {a.x, a.y, a.z, a.w};
            float brr[4] = {b.x, b.y, b.z, b.w};
            #pragma unroll
            for (int iy = 0; iy < 4; ++iy)
                #pragma unroll
                for (int ix = 0; ix < 4; ++ix)
                    acc[iy][ix] += ar[iy] * brr[ix];
        }
        __syncthreads();
    }

    const int r0 = br + tx * 4;
    float4 bias;
    bias.x = b_ih[r0+0] + b_hh[r0+0];
    bias.y = b_ih[r0+1] + b_hh[r0+1];
    bias.z = b_ih[r0+2] + b_hh[r0+2];
    bias.w = b_ih[r0+3] + b_hh[r0+3];
    #pragma unroll
    for (int iy = 0; iy < 4; ++iy) {
        float4 o;
        o.x = acc[iy][0] + bias.x;
        o.y = acc[iy][1] + bias.y;
        o.z = acc[iy][2] + bias.z;
        o.w = acc[iy][3] + bias.w;
        *(float4*)(xg + (size_t)(bt + ty * 4 + iy) * G4 + r0) = o;
    }
}

// ---------------------------------------------------------------------------
__device__ __forceinline__ float fast_sigmoid(float x) {
    x = fminf(fmaxf(x, -30.f), 30.f);
    return __builtin_amdgcn_rcpf(1.0f + __expf(-x));
}
__device__ __forceinline__ float fast_tanh(float x) {
    x = fminf(fmaxf(x, -15.f), 15.f);
    float e = __expf(2.0f * x);
    return (e - 1.0f) * __builtin_amdgcn_rcpf(e + 1.0f);
}

__device__ __forceinline__ unsigned long long mb_load(const unsigned long long* p) {
    return __hip_atomic_load(p, __ATOMIC_RELAXED, __HIP_MEMORY_SCOPE_AGENT);
}

// ---------------------------------------------------------------------------
// Kernel 2: persistent cooperative LSTM scan — full-line mailbox writes.
//
// 64 WGs x 1024 threads. Wave wv (0..15) of WG w owns h element j = w*16+wv.
// Lane layout: q = lane>>4 = gate (i,f,g,o); kc = lane&15 = 64-float h chunk.
// Thread holds W_hh[q*1024+j][kc*64 .. +64) permanently in 64 VGPRs.
//
// Mailbox: hbuf[parity(2)][1024] u64 entries (tag<<32 | f32bits).
//  - PRODUCER (full-line writes): the WG's 16 h values are gathered in LDS
//    (hout), then after barrier B2 wave 0's lanes 0..15 store the 16 tagged
//    entries with ONE global_store_dwordx2 -> two full 64B lines, no
//    partial-line RMW at the memory side (R2's hidden FETCH/latency cost).
//  - CONSUMER: thread tid polls entry tid of the current parity, 4-deep
//    pipelined so the poll issue period is ~L/4.
// Slot-reuse safety: tag t+1 (parity p^1) is stored only after this WG's
// step-t polls observed ALL tag-t entries, which happen-after every WG's
// tag-t stores, which happen-after (program order + B2 + data dependence)
// those WGs' reads of parity-p^1 slots at step t-1. Poison 0xAA.. never
// matches a tag (tags <= 4096).
// Two barriers/step: B1 (h staged in LDS before matvec), B2 (hout complete
// before the line store; also makes single-buffered hs/xgs safe).
// ---------------------------------------------------------------------------
__global__ __launch_bounds__(1024) void lstm_kernel(
    const float* __restrict__ xg,
    const float* __restrict__ W_hh,
    const float* __restrict__ h0,
    const float* __restrict__ c0,
    unsigned long long* __restrict__ hbuf,   // 2 * 1024 entries
    float* __restrict__ out)
{
    const int w    = blockIdx.x;   // 0..63
    const int tid  = threadIdx.x;  // 0..1023
    const int lane = tid & 63;
    const int wv   = tid >> 6;     // wave 0..15 -> h element j = w*16+wv
    const int q    = lane >> 4;    // gate 0..3
    const int kc   = lane & 15;    // h chunk index
    const int j    = w * 16 + wv;
    const int row  = q * HID + j;

    // Persistent W_hh fragment in 64 VGPRs.
    float wreg[64];
    {
        const float* wp = W_hh + (size_t)row * HID + kc * 64;
        #pragma unroll
        for (int m = 0; m < 16; ++m) {
            float4 v = *(const float4*)(wp + 4 * m);
            wreg[4*m+0] = v.x; wreg[4*m+1] = v.y; wreg[4*m+2] = v.z; wreg[4*m+3] = v.w;
        }
    }

    float c = c0[j];

    // Seed h0 with tag 0 (parity 0): wave 0 lanes 0..15 -> one dwordx2 store,
    // two full 64B lines for this WG's 16 entries.
    if (wv == 0 && lane < 16) {
        unsigned long long pk =
            (unsigned long long)__float_as_uint(h0[w * 16 + lane]);
        __hip_atomic_store(hbuf + w * 16 + lane, pk,
                           __ATOMIC_RELAXED, __HIP_MEMORY_SCOPE_AGENT);
    }

    __shared__ __align__(16) float hs[16 * 68];  // staged h (single buffer)
    __shared__ float xgs[64];                    // xg: gate q, elem wv -> q*16+wv
    __shared__ float hout[16];                   // this WG's 16 new h values

    const int lofs = (tid >> 6) * 68 + (tid & 63);
    const bool hasx = (tid < 64);
    const size_t xgofs = (size_t)(tid >> 4) * HID + w * 16 + (tid & 15);

    for (int t = 0; t < SEQ; ++t) {
        const int par = t & 1;
        const unsigned long long* slot = hbuf + (size_t)par * 1024 + tid;

        // xg load issued before the poll; latency hides under the wait.
        float xv = 0.f;
        if (hasx) xv = xg[(size_t)t * G4 + xgofs];

        // 4-deep pipelined poll of this thread's single entry.
        const unsigned int tg = (unsigned int)t;
        unsigned long long v;
        {
            unsigned long long p0 = mb_load(slot);
            unsigned long long p1 = mb_load(slot);
            unsigned long long p2 = mb_load(slot);
            unsigned long long p3 = mb_load(slot);
            for (;;) {
                if ((unsigned int)(p0 >> 32) == tg) { v = p0; break; }
                p0 = mb_load(slot);
                if ((unsigned int)(p1 >> 32) == tg) { v = p1; break; }
                p1 = mb_load(slot);
                if ((unsigned int)(p2 >> 32) == tg) { v = p2; break; }
                p2 = mb_load(slot);
                if ((unsigned int)(p3 >> 32) == tg) { v = p3; break; }
                p3 = mb_load(slot);
            }
        }

        hs[lofs] = __uint_as_float((unsigned int)v);
        if (hasx) xgs[tid] = xv;
        __syncthreads();  // B1

        // dot(wreg, h chunk kc): 16 x ds_read_b128 (2-way bank alias = free).
        const float* hp = hs + kc * 68;
        float sx = 0.f, sy = 0.f, sz = 0.f, sw = 0.f;
        #pragma unroll
        for (int m = 0; m < 16; ++m) {
            float4 hv = *(const float4*)(hp + 4 * m);
            sx += wreg[4*m+0] * hv.x;
            sy += wreg[4*m+1] * hv.y;
            sz += wreg[4*m+2] * hv.z;
            sw += wreg[4*m+3] * hv.w;
        }
        float s = (sx + sy) + (sz + sw);
        s += __shfl_xor(s, 1);
        s += __shfl_xor(s, 2);
        s += __shfl_xor(s, 4);
        s += __shfl_xor(s, 8);
        float gi = __shfl(s, 0)  + xgs[ 0 + wv];
        float gf = __shfl(s, 16) + xgs[16 + wv];
        float gg = __shfl(s, 32) + xgs[32 + wv];
        float go = __shfl(s, 48) + xgs[48 + wv];

        float ig = fast_sigmoid(gi);
        float fg = fast_sigmoid(gf);
        float gc = fast_tanh(gg);
        float og = fast_sigmoid(go);
        c = fg * c + ig * gc;
        float h = og * fast_tanh(c);

        if (lane == 0) hout[wv] = h;
        __syncthreads();  // B2

        // Wave 0, lanes 0..15: publish the WG's 16 tagged entries as one
        // dwordx2 store -> two contiguous full 64B lines (no RMW).
        if (wv == 0 && lane < 16) {
            unsigned long long pk =
                ((unsigned long long)(unsigned int)(t + 1) << 32) |
                (unsigned long long)__float_as_uint(hout[lane]);
            __hip_atomic_store(
                hbuf + (size_t)((t + 1) & 1) * 1024 + w * 16 + lane, pk,
                __ATOMIC_RELAXED, __HIP_MEMORY_SCOPE_AGENT);
        }
        // hs/xgs single buffer is safe: next step's writes are ordered after
        // B2 (program order), which orders them after all this-step reads.
    }

    // ------------------- final log_softmax (WG 0 only) -------------------
    if (w != 0) return;

    float a;
    {
        const unsigned int tg = (unsigned int)SEQ;  // SEQ even -> parity 0
        const unsigned long long* slot = hbuf + tid;
        unsigned long long v;
        do {
            v = mb_load(slot);
        } while ((unsigned int)(v >> 32) != tg);
        a = __uint_as_float((unsigned int)v);
    }

    __shared__ float rmax[16];
    __shared__ float rsum[16];

    float lm = a;
    #pragma unroll
    for (int d = 1; d < 64; d <<= 1) lm = fmaxf(lm, __shfl_xor(lm, d));
    if (lane == 0) rmax[wv] = lm;
    __syncthreads();
    float gm = rmax[0];
    #pragma unroll
    for (int i = 1; i < 16; ++i) gm = fmaxf(gm, rmax[i]);

    float ls = expf(a - gm);
    #pragma unroll
    for (int d = 1; d < 64; d <<= 1) ls += __shfl_xor(ls, d);
    if (lane == 0) rsum[wv] = ls;
    __syncthreads();
    float tot = rsum[0];
    #pragma unroll
    for (int i = 1; i < 16; ++i) tot += rsum[i];
    const float lse = gm + logf(tot);

    out[tid] = a - lse;
}

// ---------------------------------------------------------------------------
extern "C" void kernel_launch(void* const* d_in, const int* in_sizes, int n_in,
                              void* d_out, int out_size, void* d_ws, size_t ws_size,
                              hipStream_t stream)
{
    const int*   inputs = (const int*)d_in[0];
    const float* emb    = (const float*)d_in[1];
    const float* W_ih   = (const float*)d_in[2];
    const float* W_hh   = (const float*)d_in[3];
    const float* b_ih   = (const float*)d_in[4];
    const float* b_hh   = (const float*)d_in[5];
    const float* h0     = (const float*)d_in[6];
    const float* c0     = (const float*)d_in[7];
    float* out = (float*)d_out;

    // Workspace: [0, 64MB) xg ; [64MB, +16KB) hbuf (2 x 1024 u64).
    float* xg = (float*)d_ws;
    unsigned long long* hbuf =
        (unsigned long long*)((char*)d_ws + (size_t)SEQ * G4 * sizeof(float));

    dim3 g1(G4 / 64, SEQ / 64), b1(256);
    hipLaunchKernelGGL(xg_gemm_kernel, g1, b1, 0, stream,
                       inputs, emb, W_ih, b_ih, b_hh, xg);

    void* args[] = { (void*)&xg, (void*)&W_hh, (void*)&h0, (void*)&c0,
                     (void*)&hbuf, (void*)&out };
    hipLaunchCooperativeKernel((void*)lstm_kernel, dim3(64), dim3(1024),
                               args, 0u, stream);
}

// Round 5
// 9528.929 us; speedup vs baseline: 2.3810x; 1.0357x over previous
//
#include <hip/hip_runtime.h>
#include <cmath>

// Problem constants (fixed by the reference).
#define SEQ   4096
#define INP   1024
#define HID   1024
#define G4    4096   // 4*HID

// ---------------------------------------------------------------------------
// Kernel 1: xg[t][r] = dot(emb[inputs[t]], W_ih[r]) + b_ih[r] + b_hh[r]
// 64x64 output tile per block, 256 threads, 4x4 micro-tile, fp32 VALU.
// ---------------------------------------------------------------------------
__global__ __launch_bounds__(256) void xg_gemm_kernel(
    const int* __restrict__ inputs,
    const float* __restrict__ emb,
    const float* __restrict__ W_ih,
    const float* __restrict__ b_ih,
    const float* __restrict__ b_hh,
    float* __restrict__ xg)
{
    __shared__ __align__(16) float As[16][68];
    __shared__ __align__(16) float Bs[16][68];
    __shared__ int toks[64];

    const int tid = threadIdx.x;
    const int bt = blockIdx.y * 64;
    const int br = blockIdx.x * 64;

    if (tid < 64) toks[tid] = inputs[bt + tid];
    __syncthreads();

    const int tx = tid & 15;
    const int ty = tid >> 4;
    const int si = tid >> 2;
    const int sk = (tid & 3) * 4;

    float acc[4][4] = {};

    for (int kk = 0; kk < INP; kk += 16) {
        float4 av = *(const float4*)(emb  + (size_t)toks[si] * INP + kk + sk);
        float4 bv = *(const float4*)(W_ih + (size_t)(br + si) * INP + kk + sk);
        As[sk+0][si] = av.x; As[sk+1][si] = av.y; As[sk+2][si] = av.z; As[sk+3][si] = av.w;
        Bs[sk+0][si] = bv.x; Bs[sk+1][si] = bv.y; Bs[sk+2][si] = bv.z; Bs[sk+3][si] = bv.w;
        __syncthreads();
        #pragma unroll
        for (int k = 0; k < 16; ++k) {
            float4 a = *(const float4*)&As[k][ty * 4];
            float4 b = *(const float4*)&Bs[k][tx * 4];
            float ar[4] = {a.x, a.y, a.z, a.w};
            float brr[4] = {b.x, b.y, b.z, b.w};
            #pragma unroll
            for (int iy = 0; iy < 4; ++iy)
                #pragma unroll
                for (int ix = 0; ix < 4; ++ix)
                    acc[iy][ix] += ar[iy] * brr[ix];
        }
        __syncthreads();
    }

    const int r0 = br + tx * 4;
    float4 bias;
    bias.x = b_ih[r0+0] + b_hh[r0+0];
    bias.y = b_ih[r0+1] + b_hh[r0+1];
    bias.z = b_ih[r0+2] + b_hh[r0+2];
    bias.w = b_ih[r0+3] + b_hh[r0+3];
    #pragma unroll
    for (int iy = 0; iy < 4; ++iy) {
        float4 o;
        o.x = acc[iy][0] + bias.x;
        o.y = acc[iy][1] + bias.y;
        o.z = acc[iy][2] + bias.z;
        o.w = acc[iy][3] + bias.w;
        *(float4*)(xg + (size_t)(bt + ty * 4 + iy) * G4 + r0) = o;
    }
}

// ---------------------------------------------------------------------------
__device__ __forceinline__ float fast_sigmoid(float x) {
    x = fminf(fmaxf(x, -30.f), 30.f);
    return __builtin_amdgcn_rcpf(1.0f + __expf(-x));
}
__device__ __forceinline__ float fast_tanh(float x) {
    x = fminf(fmaxf(x, -15.f), 15.f);
    float e = __expf(2.0f * x);
    return (e - 1.0f) * __builtin_amdgcn_rcpf(e + 1.0f);
}

__device__ __forceinline__ unsigned long long mb_load(const unsigned long long* p) {
    return __hip_atomic_load(p, __ATOMIC_RELAXED, __HIP_MEMORY_SCOPE_AGENT);
}

// DPP cross-lane move (VALU pipe, not LDS). CTRL: 0xB1=xor1 (quad_perm
// [1,0,3,2]), 0x4E=xor2 ([2,3,0,1]), 0x124=row_ror:4, 0x128=row_ror:8.
template <int CTRL>
__device__ __forceinline__ float dpp_mov(float x) {
    return __int_as_float(__builtin_amdgcn_update_dpp(
        0, __float_as_int(x), CTRL, 0xF, 0xF, true));
}

// ---------------------------------------------------------------------------
// Kernel 2: persistent cooperative LSTM scan — full-line mailbox writes,
// redundancy-free LDS reads + DPP/shuffle butterfly reduction.
//
// 64 WGs x 1024 threads. Wave wv (0..15) of WG w owns h element j = w*16+wv
// and its 4 gate rows {q*1024+j}. Lane (qq=lane>>4, kc=lane&15) computes
// partial dots for ALL 4 rows over its PRIVATE 16-element h slice
// h[kc*64+qq*16 .. +16)  ->  only 4 ds_read_b128 per wave, every lane
// reading distinct data (vs 16 reads with 4x redundancy before).
// W regs: wreg[q][16] = 64 floats/thread, loaded once.
// Reduction: 64-lane butterfly of 4 accumulators. xor1/xor2/ror4/ror8 are
// DPP (VALU pipe); only xor16/xor32 use the LDS pipe (ds_swizzle).
//
// Mailbox: hbuf[parity(2)][1024] u64 (tag<<32 | f32bits), full-line stores
// by wave 0 lanes 0..15 (two 64B lines per WG, no partial-line RMW).
// Consumer polls its single entry 4-deep pipelined. Slot-reuse safety as in
// R4 (parity + tag; producer t+1 happens-after all t consumed).
// ---------------------------------------------------------------------------
__global__ __launch_bounds__(1024) void lstm_kernel(
    const float* __restrict__ xg,
    const float* __restrict__ W_hh,
    const float* __restrict__ h0,
    const float* __restrict__ c0,
    unsigned long long* __restrict__ hbuf,   // 2 * 1024 entries
    float* __restrict__ out)
{
    const int w    = blockIdx.x;   // 0..63
    const int tid  = threadIdx.x;  // 0..1023
    const int lane = tid & 63;
    const int wv   = tid >> 6;     // wave 0..15 -> h element j = w*16+wv
    const int qq   = lane >> 4;    // 16-lane group 0..3 (h-slice quarter)
    const int kc   = lane & 15;    // 64-float h chunk index
    const int j    = w * 16 + wv;

    // Persistent W fragment: wreg[q][e] = W_hh[q*1024+j][kc*64+qq*16+e].
    float wreg[4][16];
    {
        #pragma unroll
        for (int q = 0; q < 4; ++q) {
            const float* wp = W_hh + (size_t)(q * HID + j) * HID + kc * 64 + qq * 16;
            #pragma unroll
            for (int m = 0; m < 4; ++m) {
                float4 v = *(const float4*)(wp + 4 * m);
                wreg[q][4*m+0] = v.x; wreg[q][4*m+1] = v.y;
                wreg[q][4*m+2] = v.z; wreg[q][4*m+3] = v.w;
            }
        }
    }

    float c = c0[j];

    // Seed h0 with tag 0 (parity 0): wave 0 lanes 0..15, full-line store.
    if (wv == 0 && lane < 16) {
        unsigned long long pk =
            (unsigned long long)__float_as_uint(h0[w * 16 + lane]);
        __hip_atomic_store(hbuf + w * 16 + lane, pk,
                           __ATOMIC_RELAXED, __HIP_MEMORY_SCOPE_AGENT);
    }

    __shared__ __align__(16) float hs[16 * 68];  // h chunks, stride 68
    __shared__ float xgs[64];                    // xg: gate q, elem wv -> q*16+wv
    __shared__ float hout[16];                   // this WG's 16 new h values

    const int lofs = (tid >> 6) * 68 + (tid & 63);   // write slot for polled h
    const bool hasx = (tid < 64);
    const size_t xgofs = (size_t)(tid >> 4) * HID + w * 16 + (tid & 15);
    const float* hp = hs + kc * 68 + qq * 16;        // private 16-elem slice

    for (int t = 0; t < SEQ; ++t) {
        const int par = t & 1;
        const unsigned long long* slot = hbuf + (size_t)par * 1024 + tid;

        // xg load issued before the poll; latency hides under the wait.
        float xv = 0.f;
        if (hasx) xv = xg[(size_t)t * G4 + xgofs];

        // 4-deep pipelined poll of this thread's single entry.
        const unsigned int tg = (unsigned int)t;
        unsigned long long v;
        {
            unsigned long long p0 = mb_load(slot);
            unsigned long long p1 = mb_load(slot);
            unsigned long long p2 = mb_load(slot);
            unsigned long long p3 = mb_load(slot);
            for (;;) {
                if ((unsigned int)(p0 >> 32) == tg) { v = p0; break; }
                p0 = mb_load(slot);
                if ((unsigned int)(p1 >> 32) == tg) { v = p1; break; }
                p1 = mb_load(slot);
                if ((unsigned int)(p2 >> 32) == tg) { v = p2; break; }
                p2 = mb_load(slot);
                if ((unsigned int)(p3 >> 32) == tg) { v = p3; break; }
                p3 = mb_load(slot);
            }
        }

        hs[lofs] = __uint_as_float((unsigned int)v);
        if (hasx) xgs[tid] = xv;
        __syncthreads();  // B1

        // Partial dots for all 4 gate rows over the private 16-elem slice:
        // 4 ds_read_b128, all lanes distinct data.
        float p[4] = {0.f, 0.f, 0.f, 0.f};
        #pragma unroll
        for (int m = 0; m < 4; ++m) {
            float4 hv = *(const float4*)(hp + 4 * m);
            #pragma unroll
            for (int q = 0; q < 4; ++q) {
                p[q] += wreg[q][4*m+0] * hv.x;
                p[q] += wreg[q][4*m+1] * hv.y;
                p[q] += wreg[q][4*m+2] * hv.z;
                p[q] += wreg[q][4*m+3] * hv.w;
            }
        }

        // 64-lane butterfly reduction of the 4 accumulators.
        // xor1, xor2 (quad sums), ror4+ror8 (16-lane row sums): DPP / VALU.
        #pragma unroll
        for (int q = 0; q < 4; ++q) {
            p[q] += dpp_mov<0xB1>(p[q]);
            p[q] += dpp_mov<0x4E>(p[q]);
            p[q] += dpp_mov<0x124>(p[q]);
            p[q] += dpp_mov<0x128>(p[q]);
            p[q] += __shfl_xor(p[q], 16);
            p[q] += __shfl_xor(p[q], 32);
        }

        float gi = p[0] + xgs[ 0 + wv];
        float gf = p[1] + xgs[16 + wv];
        float gg = p[2] + xgs[32 + wv];
        float go = p[3] + xgs[48 + wv];

        float ig = fast_sigmoid(gi);
        float fg = fast_sigmoid(gf);
        float gc = fast_tanh(gg);
        float og = fast_sigmoid(go);
        c = fg * c + ig * gc;
        float h = og * fast_tanh(c);

        if (lane == 0) hout[wv] = h;
        __syncthreads();  // B2

        // Wave 0, lanes 0..15: publish 16 tagged entries -> two full 64B lines.
        if (wv == 0 && lane < 16) {
            unsigned long long pk =
                ((unsigned long long)(unsigned int)(t + 1) << 32) |
                (unsigned long long)__float_as_uint(hout[lane]);
            __hip_atomic_store(
                hbuf + (size_t)((t + 1) & 1) * 1024 + w * 16 + lane, pk,
                __ATOMIC_RELAXED, __HIP_MEMORY_SCOPE_AGENT);
        }
        // hs/xgs single buffer safe: next step's writes ordered after B2.
    }

    // ------------------- final log_softmax (WG 0 only) -------------------
    if (w != 0) return;

    float a;
    {
        const unsigned int tg = (unsigned int)SEQ;  // SEQ even -> parity 0
        const unsigned long long* slot = hbuf + tid;
        unsigned long long v;
        do {
            v = mb_load(slot);
        } while ((unsigned int)(v >> 32) != tg);
        a = __uint_as_float((unsigned int)v);
    }

    __shared__ float rmax[16];
    __shared__ float rsum[16];

    float lm = a;
    #pragma unroll
    for (int d = 1; d < 64; d <<= 1) lm = fmaxf(lm, __shfl_xor(lm, d));
    if (lane == 0) rmax[wv] = lm;
    __syncthreads();
    float gm = rmax[0];
    #pragma unroll
    for (int i = 1; i < 16; ++i) gm = fmaxf(gm, rmax[i]);

    float ls = expf(a - gm);
    #pragma unroll
    for (int d = 1; d < 64; d <<= 1) ls += __shfl_xor(ls, d);
    if (lane == 0) rsum[wv] = ls;
    __syncthreads();
    float tot = rsum[0];
    #pragma unroll
    for (int i = 1; i < 16; ++i) tot += rsum[i];
    const float lse = gm + logf(tot);

    out[tid] = a - lse;
}

// ---------------------------------------------------------------------------
extern "C" void kernel_launch(void* const* d_in, const int* in_sizes, int n_in,
                              void* d_out, int out_size, void* d_ws, size_t ws_size,
                              hipStream_t stream)
{
    const int*   inputs = (const int*)d_in[0];
    const float* emb    = (const float*)d_in[1];
    const float* W_ih   = (const float*)d_in[2];
    const float* W_hh   = (const float*)d_in[3];
    const float* b_ih   = (const float*)d_in[4];
    const float* b_hh   = (const float*)d_in[5];
    const float* h0     = (const float*)d_in[6];
    const float* c0     = (const float*)d_in[7];
    float* out = (float*)d_out;

    // Workspace: [0, 64MB) xg ; [64MB, +16KB) hbuf (2 x 1024 u64).
    float* xg = (float*)d_ws;
    unsigned long long* hbuf =
        (unsigned long long*)((char*)d_ws + (size_t)SEQ * G4 * sizeof(float));

    dim3 g1(G4 / 64, SEQ / 64), b1(256);
    hipLaunchKernelGGL(xg_gemm_kernel, g1, b1, 0, stream,
                       inputs, emb, W_ih, b_ih, b_hh, xg);

    void* args[] = { (void*)&xg, (void*)&W_hh, (void*)&h0, (void*)&c0,
                     (void*)&hbuf, (void*)&out };
    hipLaunchCooperativeKernel((void*)lstm_kernel, dim3(64), dim3(1024),
                               args, 0u, stream);
}